// Round 24
// baseline (84.457 us; speedup 1.0000x reference)
//
#include <hip/hip_runtime.h>

// 10 steps of anisotropic 2D heat stencil, 48x48, B=16384.
// ROUND 24: TWO IMAGES PER WAVE, INTERLEAVED AT STEP GRANULARITY.
// R23 failed because hipcc sank B's loads past A's whole compute (VGPR=84
// proved it). Here stepA/stepB alternate, so B is consumed in iteration 1:
// loads CANNOT sink, and every step's bpermute/dep chains are covered by a
// full independent other-image step (~250 VALU ops). Attacks the plateau
// invariant: wave lifetime 25-30k cyc vs 6.5k issue.
// Peak live ~200 regs (one image's src/dst pair dead while other active)
// -> waves_per_eu(2,2): 256-reg budget, 2 waves/SIMD (= measured residency).
// Per image: lane 16x4, patch 3x12 as 6 v2f/row, ping-pong Jacobi rolled x2,
// 5-op/cell R13 form, self-tied DPP ghosts (boundary lanes = dpp-invalid
// lanes keep the frozen reflect ghost free), per-row pipelined bpermutes,
// WAR-safe halo restage after row 2 (R18 ordering).
// Ghosts = reflect pad of the INITIAL state (reference pads once).

typedef float v2f __attribute__((ext_vector_type(2)));

constexpr int NXY   = 48;
constexpr int CELLS = NXY * NXY;   // 2304
constexpr int NT    = 10;
constexpr int TPB   = 64;          // one wave per block

// lane i <- lane i-1 within each 16-lane DPP row; invalid (i%16==0) keeps oldv
__device__ __forceinline__ float dpp_up(float oldv, float src) {
    return __int_as_float(__builtin_amdgcn_update_dpp(
        __float_as_int(oldv), __float_as_int(src), 0x111, 0xF, 0xF, false));
}
// lane i <- lane i+1; invalid (i%16==15) keeps oldv
__device__ __forceinline__ float dpp_dn(float oldv, float src) {
    return __int_as_float(__builtin_amdgcn_update_dpp(
        __float_as_int(oldv), __float_as_int(src), 0x101, 0xF, 0xF, false));
}

__global__ __launch_bounds__(TPB)
__attribute__((amdgpu_waves_per_eu(2, 2)))
void pde_heat_kernel(
    const float* __restrict__ u0,
    const float* __restrict__ aw,
    const float* __restrict__ bw,
    float* __restrict__ out)
{
    const int lane = threadIdx.x;
    const int r = lane & 15;       // patch-row strip (16 strips of 3 rows)
    const int c = lane >> 4;       // patch-col strip (4 strips of 12 cols)
    const long long img0 = (long long)blockIdx.x * 2;
    const float4* __restrict__ u4a = (const float4*)(u0 + img0 * CELLS);
    const float4* __restrict__ u4b = u4a + (CELLS / 4);
    float4*       __restrict__ o4a = (float4*)(out + img0 * CELLS);
    float4*       __restrict__ o4b = o4a + (CELLS / 4);

    const int fb = r * 36 + c * 3; // float4 index of patch (row0, col0)

    // ---- both images' loads issued up front (18 x dwordx4) ----
    v2f A[3][6], B[3][6];
    #pragma unroll
    for (int ii = 0; ii < 3; ++ii)
        #pragma unroll
        for (int k = 0; k < 3; ++k) {
            float4 t = u4a[fb + 12 * ii + k];
            A[ii][2*k]   = (v2f){t.x, t.y};
            A[ii][2*k+1] = (v2f){t.z, t.w};
        }
    #pragma unroll
    for (int ii = 0; ii < 3; ++ii)
        #pragma unroll
        for (int k = 0; k < 3; ++k) {
            float4 t = u4b[fb + 12 * ii + k];
            B[ii][2*k]   = (v2f){t.x, t.y};
            B[ii][2*k+1] = (v2f){t.z, t.w};
        }

    // ---- coefficients: image-independent, computed once ----
    // (v_sin/v_cos take REVOLUTIONS: sin(2pi*x) = v_sin(x))
    // alpha(i) scales axis-0 diff: 0.5*dt/dx^2 = 1.152 ; beta(j): dt/dy^2 = 2.304
    const float a0 = aw[0], a1 = aw[1], a2 = aw[2];
    const float b0 = bw[0], b1 = bw[1], b2 = bw[2];
    float ca[3];
    #pragma unroll
    for (int ii = 0; ii < 3; ++ii) {
        float y = (float)(3 * r + ii) * (1.0f / 47.0f);
        ca[ii] = 1.152f * (a0 + a1 * __builtin_amdgcn_sinf(y)
                              + a2 * __builtin_amdgcn_sinf(2.0f * y));
    }
    v2f cb2[6];
    #pragma unroll
    for (int k = 0; k < 6; ++k) {
        float x0 = (float)(12 * c + 2 * k)     * (1.0f / 47.0f);
        float x1 = (float)(12 * c + 2 * k + 1) * (1.0f / 47.0f);
        cb2[k].x = 2.304f * (b0 + b1 * __builtin_amdgcn_cosf(x0)
                                + b2 * __builtin_amdgcn_cosf(2.0f * x0));
        cb2[k].y = 2.304f * (b0 + b1 * __builtin_amdgcn_cosf(x1)
                                + b2 * __builtin_amdgcn_cosf(2.0f * x1));
    }

    const int laneL = lane - 16, laneR = lane + 16;
    const bool cLft = (c == 0), cRgt = (c == 3);

    // ---- two independent halo-state sets ----
    v2f abA[6], hbA[6], abB[6], hbB[6];
    float gHA[3], hlpA[3], hrpA[3], gHB[3], hlpB[3], hrpB[3];

    // init halo state from an image's INITIAL buffer. Frozen ghosts:
    // top (r==0) = row 1 = own u[1]; bottom (r==15) = row 46 = own u[1];
    // boundary lanes are exactly the dpp-invalid lanes -> stay frozen.
    auto prime = [&](const v2f (&u)[3][6], v2f (&ab)[6], v2f (&hb)[6],
                     float (&gH)[3], float (&hlp)[3], float (&hrp)[3]) {
        #pragma unroll
        for (int k = 0; k < 6; ++k) { ab[k] = u[1][k]; hb[k] = u[1][k]; }
        #pragma unroll
        for (int k = 0; k < 6; ++k) {
            ab[k].x = dpp_up(ab[k].x, u[2][k].x);
            ab[k].y = dpp_up(ab[k].y, u[2][k].y);
            hb[k].x = dpp_dn(hb[k].x, u[0][k].x);
            hb[k].y = dpp_dn(hb[k].y, u[0][k].y);
        }
        #pragma unroll
        for (int ii = 0; ii < 3; ++ii)
            gH[ii] = cLft ? u[ii][0].y : u[ii][5].x;
        #pragma unroll
        for (int ii = 0; ii < 3; ++ii) {
            hlp[ii] = __shfl(u[ii][5].y, laneL);   // left nb's col 11
            hrp[ii] = __shfl(u[ii][0].x, laneR);   // right nb's col 0
        }
    };

    // one cell-pair: u' = cv + ca*(up+dn-2cv) + cb*(l+r-2cv)
    auto cellpair = [&](int ii, int k, const v2f (&rowU)[6], const v2f (&rowM)[6],
                        const v2f (&rowD)[6], float lf, float rt) -> v2f {
        v2f cv = rowM[k];
        v2f s1 = rowU[k] + rowD[k];
        v2f s2;
        s2.x = lf + cv.y;
        s2.y = cv.x + rt;
        v2f uxx = s1 - 2.0f * cv;
        v2f uyy = s2 - 2.0f * cv;
        return cv + ca[ii] * uxx + cb2[k] * uyy;
    };

    // one Jacobi step src->dst on the given halo-state set
    auto step = [&](const v2f (&src)[3][6], v2f (&dst)[3][6],
                    v2f (&ab)[6], v2f (&hb)[6], const float (&gH)[3],
                    float (&hlp)[3], float (&hrp)[3]) {
        float hl[3], hr[3];
        #pragma unroll
        for (int ii = 0; ii < 3; ++ii) {
            hl[ii] = cLft ? gH[ii] : hlp[ii];
            hr[ii] = cRgt ? gH[ii] : hrp[ii];
        }
        #pragma unroll
        for (int ii = 0; ii < 3; ++ii) {
            const v2f (&rowU)[6] = (ii == 0) ? ab : src[ii - 1];
            const v2f (&rowD)[6] = (ii == 2) ? hb : src[ii + 1];
            #pragma unroll
            for (int k = 1; k < 5; ++k)
                dst[ii][k] = cellpair(ii, k, rowU, src[ii], rowD,
                                      src[ii][k-1].y, src[ii][k+1].x);
            dst[ii][0] = cellpair(ii, 0, rowU, src[ii], rowD,
                                  hl[ii], src[ii][1].x);
            dst[ii][5] = cellpair(ii, 5, rowU, src[ii], rowD,
                                  src[ii][4].y, hr[ii]);
            // next-step shuffles for this row (hl/hr already latched)
            hlp[ii] = __shfl(dst[ii][5].y, laneL);
            hrp[ii] = __shfl(dst[ii][0].x, laneR);
            if (ii == 2) {
                // vertical halos restaged AFTER all same-step consumers
                #pragma unroll
                for (int k = 0; k < 6; ++k) {
                    ab[k].x = dpp_up(ab[k].x, dst[2][k].x);
                    ab[k].y = dpp_up(ab[k].y, dst[2][k].y);
                    hb[k].x = dpp_dn(hb[k].x, dst[0][k].x);
                    hb[k].y = dpp_dn(hb[k].y, dst[0][k].y);
                }
            }
        }
    };

    prime(A, abA, hbA, gHA, hlpA, hrpA);
    prime(B, abB, hbB, gHB, hlpB, hrpB);

    // ---- interleaved time loop: A and B alternate per step ----
    #pragma unroll 1
    for (int it = 0; it < NT / 2; ++it) {
        v2f mA[3][6], mB[3][6];
        step(A,  mA, abA, hbA, gHA, hlpA, hrpA);
        step(B,  mB, abB, hbB, gHB, hlpB, hrpB);
        step(mA, A,  abA, hbA, gHA, hlpA, hrpA);
        step(mB, B,  abB, hbB, gHB, hlpB, hrpB);
    }

    // ---- stores ----
    #pragma unroll
    for (int ii = 0; ii < 3; ++ii)
        #pragma unroll
        for (int k = 0; k < 3; ++k) {
            float4 t;
            t.x = A[ii][2*k].x;   t.y = A[ii][2*k].y;
            t.z = A[ii][2*k+1].x; t.w = A[ii][2*k+1].y;
            o4a[fb + 12 * ii + k] = t;
        }
    #pragma unroll
    for (int ii = 0; ii < 3; ++ii)
        #pragma unroll
        for (int k = 0; k < 3; ++k) {
            float4 t;
            t.x = B[ii][2*k].x;   t.y = B[ii][2*k].y;
            t.z = B[ii][2*k+1].x; t.w = B[ii][2*k+1].y;
            o4b[fb + 12 * ii + k] = t;
        }
}

extern "C" void kernel_launch(void* const* d_in, const int* in_sizes, int n_in,
                              void* d_out, int out_size, void* d_ws, size_t ws_size,
                              hipStream_t stream) {
    const float* u0 = (const float*)d_in[0];
    const float* aw = (const float*)d_in[1];
    const float* bw = (const float*)d_in[2];
    float* out = (float*)d_out;

    const int B = in_sizes[0] / CELLS;   // 16384
    pde_heat_kernel<<<B / 2, TPB, 0, stream>>>(u0, aw, bw, out);
}

// Round 25
// 75.726 us; speedup vs baseline: 1.1153x; 1.1153x over previous
//
#include <hip/hip_runtime.h>

// 10 steps of anisotropic 2D heat stencil, 48x48, B=16384.
// FINAL STRUCTURE (best = R19, 75.8us): wave = image = block (TPB=64),
// grid 16384. Lane layout 16x4: (r,c)=(lane&15, lane>>4), patch 3x12 as
// 6 v2f/row -> packed v_pk_add/fma_f32. Double-buffered Jacobi, FULL
// 10-step unroll, 5-op/cell (cc=1-2ca-2cb precomp), self-tied DPP ghosts
// (boundary lanes are exactly the dpp-invalid lanes -> keep the frozen
// reflect ghost at zero cost), per-row pipelined bpermute halos, WAR-safe
// vertical-halo restage after row 2.
// R25 refinement: hl/hr latched PER ROW (not all at step top) -> first
// consume waits lgkmcnt(4) not lgkmcnt(0); rows 0-1 cover row 2's
// late-issued shuffles. Latch(read) precedes restage(write) per row: safe.
// Ghosts = reflect pad of the INITIAL state (reference pads once).
// Plateau evidence (R13-R24): block width 64/256/512, persistent waves,
// dual-image ILP x2 (both phasings) all land 76-87us; latency-bound
// equilibrium at ~2 waves/SIMD. This kernel is the best-known point.

typedef float v2f __attribute__((ext_vector_type(2)));

constexpr int NXY   = 48;
constexpr int CELLS = NXY * NXY;     // 2304
constexpr int NT    = 10;
constexpr int TPB   = 64;            // one wave per block

// lane i <- lane i-1 within each 16-lane DPP row; invalid (i%16==0) keeps oldv
__device__ __forceinline__ float dpp_up(float oldv, float src) {
    return __int_as_float(__builtin_amdgcn_update_dpp(
        __float_as_int(oldv), __float_as_int(src), 0x111, 0xF, 0xF, false));
}
// lane i <- lane i+1; invalid (i%16==15) keeps oldv
__device__ __forceinline__ float dpp_dn(float oldv, float src) {
    return __int_as_float(__builtin_amdgcn_update_dpp(
        __float_as_int(oldv), __float_as_int(src), 0x101, 0xF, 0xF, false));
}

__global__ __launch_bounds__(TPB)
__attribute__((amdgpu_waves_per_eu(2, 4)))
void pde_heat_kernel(
    const float* __restrict__ u0,
    const float* __restrict__ aw,
    const float* __restrict__ bw,
    float* __restrict__ out)
{
    const int lane = threadIdx.x;
    const int img  = blockIdx.x;
    const int r = lane & 15;         // patch-row strip (16 strips of 3 rows)
    const int c = lane >> 4;         // patch-col strip (4 strips of 12 cols)
    const float4* __restrict__ u4 = (const float4*)(u0 + (long long)img * CELLS);
    float4*       __restrict__ o4 = (float4*)(out + (long long)img * CELLS);

    const int fb = r * 36 + c * 3;   // float4 index of patch (row0, col0)

    // ---- direct load: 9 x global_load_dwordx4 -> 6 x v2f per row ----
    v2f v[3][6], w[3][6];
    #pragma unroll
    for (int ii = 0; ii < 3; ++ii)
        #pragma unroll
        for (int k = 0; k < 3; ++k) {
            float4 t = u4[fb + 12 * ii + k];
            v[ii][2*k]   = (v2f){t.x, t.y};
            v[ii][2*k+1] = (v2f){t.z, t.w};
        }

    // ---- coefficients (v_sin/v_cos take REVOLUTIONS: sin(2pi*x) = v_sin(x)) ----
    // alpha(i) scales axis-0 diff: 0.5*dt/dx^2 = 1.152 ; beta(j): dt/dy^2 = 2.304
    const float a0 = aw[0], a1 = aw[1], a2 = aw[2];
    const float b0 = bw[0], b1 = bw[1], b2 = bw[2];
    float ca[3];
    #pragma unroll
    for (int ii = 0; ii < 3; ++ii) {
        float y = (float)(3 * r + ii) * (1.0f / 47.0f);
        ca[ii] = 1.152f * (a0 + a1 * __builtin_amdgcn_sinf(y)
                              + a2 * __builtin_amdgcn_sinf(2.0f * y));
    }
    v2f cb2[6];
    #pragma unroll
    for (int k = 0; k < 6; ++k) {
        float x0 = (float)(12 * c + 2 * k)     * (1.0f / 47.0f);
        float x1 = (float)(12 * c + 2 * k + 1) * (1.0f / 47.0f);
        cb2[k].x = 2.304f * (b0 + b1 * __builtin_amdgcn_cosf(x0)
                                + b2 * __builtin_amdgcn_cosf(2.0f * x0));
        cb2[k].y = 2.304f * (b0 + b1 * __builtin_amdgcn_cosf(x1)
                                + b2 * __builtin_amdgcn_cosf(2.0f * x1));
    }
    v2f cc[3][6];                    // center coeff cc = 1 - 2ca - 2cb
    #pragma unroll
    for (int ii = 0; ii < 3; ++ii) {
        float t = 1.0f - 2.0f * ca[ii];
        #pragma unroll
        for (int k = 0; k < 6; ++k) {
            cc[ii][k].x = t - 2.0f * cb2[k].x;
            cc[ii][k].y = t - 2.0f * cb2[k].y;
        }
    }

    // ---- persistent halo regs, init'd to the frozen ghost ----
    // top ghost (r==0) = u0 row 1 = own v[1]; bottom (r==15) = row 46 = own
    // v[1]. Boundary lanes are exactly the dpp-invalid lanes -> stay frozen.
    v2f ab[6], hb[6];
    #pragma unroll
    for (int k = 0; k < 6; ++k) { ab[k] = v[1][k]; hb[k] = v[1][k]; }

    float gH[3];   // frozen horizontal ghosts: col 1 / col 46 (own initial)
    #pragma unroll
    for (int ii = 0; ii < 3; ++ii) gH[ii] = (c == 0) ? v[ii][0].y : v[ii][5].x;

    const int laneL = lane - 16, laneR = lane + 16;
    const bool cLft = (c == 0), cRgt = (c == 3);

    // prime both halo pipelines for step 0 (from initial state)
    #pragma unroll
    for (int k = 0; k < 6; ++k) {
        ab[k].x = dpp_up(ab[k].x, v[2][k].x);
        ab[k].y = dpp_up(ab[k].y, v[2][k].y);
        hb[k].x = dpp_dn(hb[k].x, v[0][k].x);
        hb[k].y = dpp_dn(hb[k].y, v[0][k].y);
    }
    float hlp[3], hrp[3];
    #pragma unroll
    for (int ii = 0; ii < 3; ++ii) {
        hlp[ii] = __shfl(v[ii][5].y, laneL);   // left neighbor's col 11
        hrp[ii] = __shfl(v[ii][0].x, laneR);   // right neighbor's col 0
    }

    // one cell-pair update (5 packed ops + 2 scalar adds)
    auto cellpair = [&](int ii, int k, const v2f (&rowU)[6], const v2f (&rowM)[6],
                        const v2f (&rowD)[6], float lf, float rt) -> v2f {
        v2f cv = rowM[k];
        v2f s1 = rowU[k] + rowD[k];
        v2f s2;
        s2.x = lf + cv.y;
        s2.y = cv.x + rt;
        return cc[ii][k] * cv + ca[ii] * s1 + cb2[k] * s2;
    };

    // one Jacobi step: per-row hl/hr latch (lgkmcnt(4) at first consume);
    // interior pairs first; shuffles issued per-row after the row finalizes;
    // ab/hb restaged at ii==2 AFTER all same-step consumers (WAR-safe).
    auto step = [&](const v2f (&src)[3][6], v2f (&dst)[3][6], bool stage) {
        #pragma unroll
        for (int ii = 0; ii < 3; ++ii) {
            const v2f (&rowU)[6] = (ii == 0) ? ab : src[ii - 1];
            const v2f (&rowD)[6] = (ii == 2) ? hb : src[ii + 1];
            // interior pairs k=1..4: no halos needed (cover halo waits)
            #pragma unroll
            for (int k = 1; k < 5; ++k)
                dst[ii][k] = cellpair(ii, k, rowU, src[ii], rowD,
                                      src[ii][k-1].y, src[ii][k+1].x);
            // latch THIS row's halos just before use (read precedes restage)
            const float hlv = cLft ? gH[ii] : hlp[ii];
            const float hrv = cRgt ? gH[ii] : hrp[ii];
            dst[ii][0] = cellpair(ii, 0, rowU, src[ii], rowD,
                                  hlv, src[ii][1].x);
            dst[ii][5] = cellpair(ii, 5, rowU, src[ii], rowD,
                                  src[ii][4].y, hrv);
            if (stage) {
                // this row's next-step horizontal halos
                hlp[ii] = __shfl(dst[ii][5].y, laneL);
                hrp[ii] = __shfl(dst[ii][0].x, laneR);
                if (ii == 2) {
                    // vertical halos for next step - AFTER all consumers
                    #pragma unroll
                    for (int k = 0; k < 6; ++k) {
                        ab[k].x = dpp_up(ab[k].x, dst[2][k].x);
                        ab[k].y = dpp_up(ab[k].y, dst[2][k].y);
                        hb[k].x = dpp_dn(hb[k].x, dst[0][k].x);
                        hb[k].y = dpp_dn(hb[k].y, dst[0][k].y);
                    }
                }
            }
        }
    };

    // ---- time loop: FULLY UNROLLED (buffer choice folds statically) ----
    #pragma unroll
    for (int t = 0; t < NT; ++t) {
        if ((t & 1) == 0) step(v, w, t != NT - 1);
        else              step(w, v, t != NT - 1);
    }
    // NT even -> final state in v

    // ---- direct store: 9 x global_store_dwordx4 ----
    #pragma unroll
    for (int ii = 0; ii < 3; ++ii)
        #pragma unroll
        for (int k = 0; k < 3; ++k) {
            float4 t;
            t.x = v[ii][2*k].x;   t.y = v[ii][2*k].y;
            t.z = v[ii][2*k+1].x; t.w = v[ii][2*k+1].y;
            o4[fb + 12 * ii + k] = t;
        }
}

extern "C" void kernel_launch(void* const* d_in, const int* in_sizes, int n_in,
                              void* d_out, int out_size, void* d_ws, size_t ws_size,
                              hipStream_t stream) {
    const float* u0 = (const float*)d_in[0];
    const float* aw = (const float*)d_in[1];
    const float* bw = (const float*)d_in[2];
    float* out = (float*)d_out;

    const int B = in_sizes[0] / CELLS;   // 16384
    pde_heat_kernel<<<B, TPB, 0, stream>>>(u0, aw, bw, out);
}